// Round 6
// baseline (101.487 us; speedup 1.0000x reference)
//
#include <hip/hip_runtime.h>
#include <math.h>

// QKV attention: qkv [64][192][2048] fp32 -> out [64][64][2048] fp32
// prep: K -> Kt [b][s][c] bf16, V -> Vb [b][c][t] bf16 (d_ws)
// attn: swapped-QK flash, bf16 MFMA 16x16x32, no-max softmax (v_exp_f32),
//       in-register P transpose (cvt_pk + permlane swaps), VALU denominator,
//       2 waves x 64t per block (TQ=128), 4 blocks/CU, global_load_lds dbuf.

#define B_   64
#define CH_  64
#define T_   2048
#define TQ   128
#define SB   64
#define NIT  (T_ / SB)

typedef __attribute__((ext_vector_type(8))) short short8;
typedef __attribute__((ext_vector_type(4))) float f32x4;
typedef __attribute__((ext_vector_type(4))) unsigned short us4;
typedef __attribute__((ext_vector_type(8))) unsigned short us8;

static __device__ __forceinline__ unsigned short f2bf(float f) {
    union { float f; unsigned u; } v; v.f = f;
    unsigned r = v.u + 0x7FFFu + ((v.u >> 16) & 1u);   // RNE
    return (unsigned short)(r >> 16);
}

static __device__ __forceinline__ short8 ld_contig(const unsigned short* p) {
    return *(const short8*)p;                  // 16B-aligned -> ds_read_b128
}

static __device__ __forceinline__ short8 ld_strided(const unsigned short* p, int stride) {
    short8 r;
#pragma unroll
    for (int j = 0; j < 8; ++j) r[j] = (short)p[j * stride];
    return r;
}

static __device__ __forceinline__ void gl_lds16(const unsigned short* g, unsigned short* l) {
    __builtin_amdgcn_global_load_lds(
        (const __attribute__((address_space(1))) unsigned int*)g,
        (__attribute__((address_space(3))) unsigned int*)l, 16, 0, 0);
}

static __device__ __forceinline__ float vexp2(float x) {
#if __has_builtin(__builtin_amdgcn_exp2f)
    return __builtin_amdgcn_exp2f(x);          // single v_exp_f32
#else
    float r;
    asm("v_exp_f32 %0, %1\n\ts_nop 1" : "=v"(r) : "v"(x));
    return r;
#endif
}

static __device__ __forceinline__ unsigned cvtpk(float lo, float hi) {
    unsigned r;
    asm("v_cvt_pk_bf16_f32 %0, %1, %2" : "=v"(r) : "v"(lo), "v"(hi));
    return r;
}

static __device__ __forceinline__ void pl_swap(unsigned& a, unsigned& b) {
    asm volatile("v_permlane32_swap_b32 %0, %1" : "+v"(a), "+v"(b));
    asm volatile("v_permlane16_swap_b32 %0, %1" : "+v"(a), "+v"(b));
}

// ---------------- prep: K transpose + V convert ----------------
__global__ __launch_bounds__(256) void qkv_prep(const float* __restrict__ qkv,
                                                unsigned short* __restrict__ Ktg,
                                                unsigned short* __restrict__ Vbg)
{
    __shared__ float Tl[64][65];
    const int tid = threadIdx.x;
    const int b   = blockIdx.x >> 5;
    const int t0  = (blockIdx.x & 31) * 64;
    const float* Kp = qkv + (size_t)b * (3 * CH_ * T_) + (size_t)CH_ * T_;
    const float* Vp = Kp + (size_t)CH_ * T_;

    {
        const int c = tid & 63, fq = tid >> 6;
#pragma unroll
        for (int k = 0; k < 4; ++k) {
            const int tl = 16 * fq + 4 * k;
            const float4 v = *(const float4*)(Kp + (size_t)c * T_ + t0 + tl);
            Tl[c][tl] = v.x; Tl[c][tl + 1] = v.y; Tl[c][tl + 2] = v.z; Tl[c][tl + 3] = v.w;
        }
    }
    {
        const int c = tid >> 2, tq = (tid & 3) * 16;
        unsigned short* vout = Vbg + (size_t)b * CH_ * T_ + (size_t)c * T_ + t0 + tq;
        const float* vin = Vp + (size_t)c * T_ + t0 + tq;
#pragma unroll
        for (int k = 0; k < 2; ++k) {
            const float4 a  = *(const float4*)(vin + 8 * k);
            const float4 bq = *(const float4*)(vin + 8 * k + 4);
            us8 w8;
            w8[0]=f2bf(a.x);  w8[1]=f2bf(a.y);  w8[2]=f2bf(a.z);  w8[3]=f2bf(a.w);
            w8[4]=f2bf(bq.x); w8[5]=f2bf(bq.y); w8[6]=f2bf(bq.z); w8[7]=f2bf(bq.w);
            *(us8*)(vout + 8 * k) = w8;
        }
    }
    __syncthreads();
    {
        const int cb = tid & 7;
#pragma unroll
        for (int ot = 0; ot < 2; ++ot) {
            const int sl = (tid >> 3) + 32 * ot;
            us8 w8;
#pragma unroll
            for (int j = 0; j < 8; ++j) w8[j] = f2bf(Tl[8 * cb + j][sl]);
            *(us8*)(Ktg + (size_t)b * T_ * CH_ + (size_t)(t0 + sl) * 64 + 8 * cb) = w8;
        }
    }
}

// ---------------- main attention: 2 waves x 64t ----------------
__global__ __launch_bounds__(128, 2) void qkv_attn6(const float* __restrict__ qkv,
                                                    const unsigned short* __restrict__ Ktg,
                                                    const unsigned short* __restrict__ Vbg,
                                                    float* __restrict__ out)
{
    __shared__ unsigned short Ks[2][64 * 64];
    __shared__ unsigned short Vs[2][64 * 64];

    const int tid  = threadIdx.x;
    const int lane = tid & 63;
    const int wid  = tid >> 6;
    const int l15  = lane & 15;
    const int h    = lane >> 4;

    int bid = blockIdx.x;
    bid = (bid & 7) * 128 + (bid >> 3);        // XCD swizzle (1024 = 8*128, bijective)
    const int b  = bid >> 4;                   // 16 t-tiles per batch
    const int t0 = (bid & 15) * TQ;
    const int tb = t0 + wid * 64;              // wave's 64 t-rows

    const float* Qp = qkv + (size_t)b * (3 * CH_ * T_);
    const unsigned short* Ktb = Ktg + (size_t)b * (T_ * CH_);
    const unsigned short* Vbb = Vbg + (size_t)b * (CH_ * T_);

    // swizzled frag-read offsets (elements)
    const int x0 = 8 * ((h)     ^ (l15 & 7));
    const int x1 = 8 * ((4 + h) ^ (l15 & 7));
    const int rb = l15 * 64;

    // staging: row r0 = tid>>3 in [0,16), 16B block xor'd with row
    const int r0 = tid >> 3;
    const int kx = (tid & 7) ^ (r0 & 7);
    const unsigned short* ksrc0 = Ktb + (size_t)r0 * 64 + 8 * kx;
    const unsigned short* vsrc0 = Vbb + (size_t)r0 * T_ + 8 * kx;
    const int dbase = 8 * wid * 64;            // wave-uniform LDS row base (shorts)

    // hoisted Q B-frags, scaled by 0.125*log2(e) (exp2-direct softmax)
    short8 aq[4][2];
#pragma unroll
    for (int ts = 0; ts < 4; ++ts)
#pragma unroll
        for (int ch = 0; ch < 2; ++ch) {
            short8 q;
#pragma unroll
            for (int j = 0; j < 8; ++j)
                q[j] = (short)f2bf(0.180336880f *
                        Qp[(size_t)(32 * ch + 8 * h + j) * T_ + tb + 16 * ts + l15]);
            aq[ts][ch] = q;
        }

    f32x4 o[4][4];
#pragma unroll
    for (int cs = 0; cs < 4; ++cs)
#pragma unroll
        for (int ts = 0; ts < 4; ++ts) o[cs][ts] = (f32x4){0.f, 0.f, 0.f, 0.f};
    float dsum[4] = {0.f, 0.f, 0.f, 0.f};
    const f32x4 zero4 = {0.f, 0.f, 0.f, 0.f};

    // prologue: stage tile 0 into buf 0 (4 K-chunks + 4 V-chunks per wave)
#pragma unroll
    for (int j = 0; j < 4; ++j) {
        gl_lds16(ksrc0 + (size_t)(16 * j) * 64,  &Ks[0][16 * j * 64 + dbase]);
        gl_lds16(vsrc0 + (size_t)(16 * j) * T_,  &Vs[0][16 * j * 64 + dbase]);
    }

    for (int it = 0; it < NIT; ++it) {
        __syncthreads();                       // tile staged, prev reads done
        const int buf = it & 1;
        if (it + 1 < NIT) {
            const int s1 = (it + 1) * SB;
            const int bo = (buf ^ 1) * 4096;
#pragma unroll
            for (int j = 0; j < 4; ++j) {
                gl_lds16(ksrc0 + (size_t)(s1 + 16 * j) * 64,
                         &Ks[0][bo + 16 * j * 64 + dbase]);
                gl_lds16(vsrc0 + (size_t)(16 * j) * T_ + s1,
                         &Vs[0][bo + 16 * j * 64 + dbase]);
            }
        }
        const unsigned short* kb = &Ks[buf][0];
        const unsigned short* vb = &Vs[buf][0];

        short8 pb[4][2];                       // P^T B-frags per ts, s-halves
#pragma unroll
        for (int half = 0; half < 2; ++half) {
            // ---- QK^T (swapped): W[s][t], lane: s=16ss+4h+r, t=tb+16ts+l15 ----
            f32x4 w[4][2];
            __builtin_amdgcn_s_setprio(1);
#pragma unroll
            for (int ss2 = 0; ss2 < 2; ++ss2) {
                const int ss = 2 * half + ss2;
                const short8 bk0 = ld_contig(kb + rb + ss * 1024 + x0);
                const short8 bk1 = ld_contig(kb + rb + ss * 1024 + x1);
#pragma unroll
                for (int ts = 0; ts < 4; ++ts) {
                    f32x4 acc = zero4;
                    acc = __builtin_amdgcn_mfma_f32_16x16x32_bf16(bk0, aq[ts][0], acc, 0, 0, 0);
                    acc = __builtin_amdgcn_mfma_f32_16x16x32_bf16(bk1, aq[ts][1], acc, 0, 0, 0);
                    w[ts][ss2] = acc;
                }
            }
            __builtin_amdgcn_s_setprio(0);
            // ---- softmax + in-register transpose into PV B-frag layout ----
#pragma unroll
            for (int ts = 0; ts < 4; ++ts) {
                float e0[4], e1[4];
#pragma unroll
                for (int r = 0; r < 4; ++r) {
                    e0[r] = vexp2(w[ts][0][r]);
                    e1[r] = vexp2(w[ts][1][r]);
                }
                dsum[ts] += ((e0[0] + e0[1]) + (e0[2] + e0[3]))
                          + ((e1[0] + e1[1]) + (e1[2] + e1[3]));
                unsigned a0 = cvtpk(e0[0], e0[1]);
                unsigned a1 = cvtpk(e0[2], e0[3]);
                unsigned b0 = cvtpk(e1[0], e1[1]);
                unsigned b1 = cvtpk(e1[2], e1[3]);
                pl_swap(a0, b0);
                pl_swap(a1, b1);
                union { short8 s8; unsigned u[4]; } u;
                u.u[0] = a0; u.u[1] = a1; u.u[2] = b0; u.u[3] = b1;
                pb[ts][half] = u.s8;
            }
        }

        // ---- PV: O[c][t] += V[c][s] * P^T[s][t] ----
        __builtin_amdgcn_s_setprio(1);
#pragma unroll
        for (int cs = 0; cs < 4; ++cs) {
            const short8 av0 = ld_contig(vb + rb + cs * 1024 + x0);
            const short8 av1 = ld_contig(vb + rb + cs * 1024 + x1);
#pragma unroll
            for (int ts = 0; ts < 4; ++ts) {
                o[cs][ts] = __builtin_amdgcn_mfma_f32_16x16x32_bf16(av0, pb[ts][0], o[cs][ts], 0, 0, 0);
                o[cs][ts] = __builtin_amdgcn_mfma_f32_16x16x32_bf16(av1, pb[ts][1], o[cs][ts], 0, 0, 0);
            }
        }
        __builtin_amdgcn_s_setprio(0);
    }

    // ---- denominator: reduce partial sums across the 4 h-groups ----
    float inv[4];
#pragma unroll
    for (int ts = 0; ts < 4; ++ts) {
        float d = dsum[ts];
        d += __shfl_xor(d, 16, 64);
        d += __shfl_xor(d, 32, 64);
        inv[ts] = 1.0f / d;
    }

    // ---- epilogue: O-frag row=c=16cs+4h+r, col=t=tb+16ts+l15 ----
    float* outp = out + (size_t)b * CH_ * T_;
#pragma unroll
    for (int cs = 0; cs < 4; ++cs)
#pragma unroll
        for (int r = 0; r < 4; ++r) {
            const size_t row = (size_t)(16 * cs + 4 * h + r) * T_;
#pragma unroll
            for (int ts = 0; ts < 4; ++ts)
                outp[row + tb + 16 * ts + l15] = o[cs][ts][r] * inv[ts];
        }
}

// ---------------- fallback (round-1 kernel, used if ws too small) ----------------
__global__ __launch_bounds__(256) void qkv_attn_fb(const float* __restrict__ qkv,
                                                   float* __restrict__ out)
{
    __shared__ unsigned short Qs[CH_][68];
    __shared__ unsigned short Ksf[CH_][68];
    __shared__ unsigned short Vsf[CH_][72];
    __shared__ unsigned short Psf[4][64][18];

    const int tid  = threadIdx.x;
    const int lane = tid & 63;
    const int wid  = tid >> 6;
    const int l15  = lane & 15;
    const int h    = lane >> 4;
    const int bidx = blockIdx.x;
    const int b    = bidx >> 5;
    const int t0   = (bidx & 31) * 64;
    const int tw   = wid * 16;

    const float* Qp = qkv + (size_t)b * (3 * CH_ * T_);
    const float* Kp = Qp + CH_ * T_;
    const float* Vp = Kp + CH_ * T_;

    const int srow = tid >> 4;
    const int scol = (tid & 15) << 2;

#pragma unroll
    for (int i = 0; i < 4; ++i) {
        const int c = srow + 16 * i;
        const float4 q = *(const float4*)(Qp + (size_t)c * T_ + t0 + scol);
        us4 w; w[0] = f2bf(q.x); w[1] = f2bf(q.y); w[2] = f2bf(q.z); w[3] = f2bf(q.w);
        *(us4*)(&Qs[c][scol]) = w;
    }
    __syncthreads();

    const short8 aq0 = ld_strided(&Qs[0 + 8 * h][tw + l15], 68);
    const short8 aq1 = ld_strided(&Qs[32 + 8 * h][tw + l15], 68);

    short8 aones;
#pragma unroll
    for (int j = 0; j < 8; ++j) aones[j] = (short)0x3F80;

    f32x4 o[4];
#pragma unroll
    for (int cs = 0; cs < 4; ++cs) o[cs] = (f32x4){0.f, 0.f, 0.f, 0.f};
    float l_run = 0.0f;
    const f32x4 zero4 = {0.f, 0.f, 0.f, 0.f};

    for (int it = 0; it < 32; ++it) {
        const int s0 = it * 64;
        __syncthreads();
#pragma unroll
        for (int i = 0; i < 4; ++i) {
            const int c = srow + 16 * i;
            const float4 kv = *(const float4*)(Kp + (size_t)c * T_ + s0 + scol);
            us4 wk; wk[0] = f2bf(kv.x); wk[1] = f2bf(kv.y); wk[2] = f2bf(kv.z); wk[3] = f2bf(kv.w);
            *(us4*)(&Ksf[c][scol]) = wk;
            const float4 vv = *(const float4*)(Vp + (size_t)c * T_ + s0 + scol);
            us4 wv; wv[0] = f2bf(vv.x); wv[1] = f2bf(vv.y); wv[2] = f2bf(vv.z); wv[3] = f2bf(vv.w);
            *(us4*)(&Vsf[c][scol]) = wv;
        }
        __syncthreads();

        f32x4 w[4];
#pragma unroll
        for (int ss = 0; ss < 4; ++ss) {
            const short8 bkl = ld_strided(&Ksf[0 + 8 * h][ss * 16 + l15], 68);
            const short8 bkh = ld_strided(&Ksf[32 + 8 * h][ss * 16 + l15], 68);
            f32x4 acc = zero4;
            acc = __builtin_amdgcn_mfma_f32_16x16x32_bf16(aq0, bkl, acc, 0, 0, 0);
            acc = __builtin_amdgcn_mfma_f32_16x16x32_bf16(aq1, bkh, acc, 0, 0, 0);
            w[ss] = acc;
        }

#pragma unroll
        for (int ss = 0; ss < 4; ++ss) {
            const float e0 = __expf(0.125f * w[ss][0]);
            const float e1 = __expf(0.125f * w[ss][1]);
            const float e2 = __expf(0.125f * w[ss][2]);
            const float e3 = __expf(0.125f * w[ss][3]);
            const unsigned p01 = (unsigned)f2bf(e0) | ((unsigned)f2bf(e1) << 16);
            const unsigned p23 = (unsigned)f2bf(e2) | ((unsigned)f2bf(e3) << 16);
            const int s = ss * 16 + l15;
            *(unsigned*)(&Psf[wid][s][4 * h]) = p01;
            *(unsigned*)(&Psf[wid][s][4 * h + 2]) = p23;
        }

        const short8 pb0 = ld_strided(&Psf[wid][0 + 8 * h][l15], 18);
        const short8 pb1 = ld_strided(&Psf[wid][32 + 8 * h][l15], 18);

        f32x4 lacc = zero4;
        lacc = __builtin_amdgcn_mfma_f32_16x16x32_bf16(aones, pb0, lacc, 0, 0, 0);
        lacc = __builtin_amdgcn_mfma_f32_16x16x32_bf16(aones, pb1, lacc, 0, 0, 0);
        l_run += lacc[0];

#pragma unroll
        for (int cs = 0; cs < 4; ++cs) {
            const short8 av0 = ld_contig(&Vsf[cs * 16 + l15][0 + 8 * h]);
            const short8 av1 = ld_contig(&Vsf[cs * 16 + l15][32 + 8 * h]);
            o[cs] = __builtin_amdgcn_mfma_f32_16x16x32_bf16(av0, pb0, o[cs], 0, 0, 0);
            o[cs] = __builtin_amdgcn_mfma_f32_16x16x32_bf16(av1, pb1, o[cs], 0, 0, 0);
        }
    }

    const float invd = 1.0f / l_run;
    float* outp = out + (size_t)b * CH_ * T_;
#pragma unroll
    for (int cs = 0; cs < 4; ++cs)
#pragma unroll
        for (int r = 0; r < 4; ++r)
            outp[(size_t)(cs * 16 + 4 * h + r) * T_ + t0 + tw + l15] = o[cs][r] * invd;
}

extern "C" void kernel_launch(void* const* d_in, const int* in_sizes, int n_in,
                              void* d_out, int out_size, void* d_ws, size_t ws_size,
                              hipStream_t stream) {
    const float* qkv = (const float*)d_in[0];
    float* outp = (float*)d_out;
    const size_t need = (size_t)2 * B_ * CH_ * T_ * sizeof(unsigned short); // 32 MB
    if (ws_size >= need) {
        unsigned short* Ktg = (unsigned short*)d_ws;
        unsigned short* Vbg = Ktg + (size_t)B_ * T_ * CH_;
        qkv_prep<<<dim3(B_ * 32), dim3(256), 0, stream>>>(qkv, Ktg, Vbg);
        qkv_attn6<<<dim3(B_ * (T_ / TQ)), dim3(128), 0, stream>>>(qkv, Ktg, Vbg, outp);
    } else {
        qkv_attn_fb<<<dim3(B_ * 32), dim3(256), 0, stream>>>(qkv, outp);
    }
}

// Round 7
// 96.452 us; speedup vs baseline: 1.0522x; 1.0522x over previous
//
#include <hip/hip_runtime.h>
#include <math.h>

// QKV attention: qkv [64][192][2048] fp32 -> out [64][64][2048] fp32
// prep: K -> Kt [b][s][c] bf16, V -> Vb [b][c][t] bf16 (d_ws)
// attn: swapped-QK flash, bf16 MFMA 16x16x32, no-max softmax (v_exp_f32),
//       in-register P transpose (cvt_pk + permlane swaps, non-volatile),
//       all-QK -> all-softmax -> PV per iter (scheduler-friendly),
//       4 waves x 32t (TQ=128), 4 blocks/CU, global_load_lds dbuf.

#define B_   64
#define CH_  64
#define T_   2048
#define TQ   128
#define SB   64
#define NIT  (T_ / SB)

typedef __attribute__((ext_vector_type(8))) short short8;
typedef __attribute__((ext_vector_type(4))) float f32x4;
typedef __attribute__((ext_vector_type(4))) unsigned short us4;
typedef __attribute__((ext_vector_type(8))) unsigned short us8;

static __device__ __forceinline__ unsigned short f2bf(float f) {
    union { float f; unsigned u; } v; v.f = f;
    unsigned r = v.u + 0x7FFFu + ((v.u >> 16) & 1u);   // RNE
    return (unsigned short)(r >> 16);
}

static __device__ __forceinline__ short8 ld_contig(const unsigned short* p) {
    return *(const short8*)p;                  // 16B-aligned -> ds_read_b128
}

static __device__ __forceinline__ short8 ld_strided(const unsigned short* p, int stride) {
    short8 r;
#pragma unroll
    for (int j = 0; j < 8; ++j) r[j] = (short)p[j * stride];
    return r;
}

static __device__ __forceinline__ void gl_lds16(const unsigned short* g, unsigned short* l) {
    __builtin_amdgcn_global_load_lds(
        (const __attribute__((address_space(1))) unsigned int*)g,
        (__attribute__((address_space(3))) unsigned int*)l, 16, 0, 0);
}

static __device__ __forceinline__ float vexp2(float x) {
#if __has_builtin(__builtin_amdgcn_exp2f)
    return __builtin_amdgcn_exp2f(x);          // single v_exp_f32
#else
    float r;
    asm("v_exp_f32 %0, %1\n\ts_nop 1" : "=v"(r) : "v"(x));
    return r;
#endif
}

static __device__ __forceinline__ unsigned cvtpk(float lo, float hi) {
    unsigned r;
    asm("v_cvt_pk_bf16_f32 %0, %1, %2" : "=v"(r) : "v"(lo), "v"(hi));
    return r;
}

// pure data op: NO volatile -> scheduler may interleave with MFMA stream
static __device__ __forceinline__ void pl_swap(unsigned& a, unsigned& b) {
    asm("v_permlane32_swap_b32 %0, %1" : "+v"(a), "+v"(b));
    asm("v_permlane16_swap_b32 %0, %1" : "+v"(a), "+v"(b));
}

// ---------------- prep: K transpose + V convert ----------------
__global__ __launch_bounds__(256) void qkv_prep(const float* __restrict__ qkv,
                                                unsigned short* __restrict__ Ktg,
                                                unsigned short* __restrict__ Vbg)
{
    __shared__ float Tl[64][65];
    const int tid = threadIdx.x;
    const int b   = blockIdx.x >> 5;
    const int t0  = (blockIdx.x & 31) * 64;
    const float* Kp = qkv + (size_t)b * (3 * CH_ * T_) + (size_t)CH_ * T_;
    const float* Vp = Kp + (size_t)CH_ * T_;

    {
        const int c = tid & 63, fq = tid >> 6;
#pragma unroll
        for (int k = 0; k < 4; ++k) {
            const int tl = 16 * fq + 4 * k;
            const float4 v = *(const float4*)(Kp + (size_t)c * T_ + t0 + tl);
            Tl[c][tl] = v.x; Tl[c][tl + 1] = v.y; Tl[c][tl + 2] = v.z; Tl[c][tl + 3] = v.w;
        }
    }
    {
        const int c = tid >> 2, tq = (tid & 3) * 16;
        unsigned short* vout = Vbg + (size_t)b * CH_ * T_ + (size_t)c * T_ + t0 + tq;
        const float* vin = Vp + (size_t)c * T_ + t0 + tq;
#pragma unroll
        for (int k = 0; k < 2; ++k) {
            const float4 a  = *(const float4*)(vin + 8 * k);
            const float4 bq = *(const float4*)(vin + 8 * k + 4);
            us8 w8;
            w8[0]=f2bf(a.x);  w8[1]=f2bf(a.y);  w8[2]=f2bf(a.z);  w8[3]=f2bf(a.w);
            w8[4]=f2bf(bq.x); w8[5]=f2bf(bq.y); w8[6]=f2bf(bq.z); w8[7]=f2bf(bq.w);
            *(us8*)(vout + 8 * k) = w8;
        }
    }
    __syncthreads();
    {
        const int cb = tid & 7;
#pragma unroll
        for (int ot = 0; ot < 2; ++ot) {
            const int sl = (tid >> 3) + 32 * ot;
            us8 w8;
#pragma unroll
            for (int j = 0; j < 8; ++j) w8[j] = f2bf(Tl[8 * cb + j][sl]);
            *(us8*)(Ktg + (size_t)b * T_ * CH_ + (size_t)(t0 + sl) * 64 + 8 * cb) = w8;
        }
    }
}

// ---------------- main attention ----------------
__global__ __launch_bounds__(256, 4) void qkv_attn7(const float* __restrict__ qkv,
                                                    const unsigned short* __restrict__ Ktg,
                                                    const unsigned short* __restrict__ Vbg,
                                                    float* __restrict__ out)
{
    __shared__ unsigned short Ks[2][64 * 64];
    __shared__ unsigned short Vs[2][64 * 64];

    const int tid  = threadIdx.x;
    const int lane = tid & 63;
    const int wid  = tid >> 6;
    const int l15  = lane & 15;
    const int h    = lane >> 4;

    int bid = blockIdx.x;
    bid = (bid & 7) * 128 + (bid >> 3);        // XCD swizzle (1024 = 8*128, bijective)
    const int b  = bid >> 4;                   // 16 t-tiles per batch
    const int t0 = (bid & 15) * TQ;
    const int tb = t0 + wid * 32;              // wave's 32 t-rows

    const float* Qp = qkv + (size_t)b * (3 * CH_ * T_);
    const unsigned short* Ktb = Ktg + (size_t)b * (T_ * CH_);
    const unsigned short* Vbb = Vbg + (size_t)b * (CH_ * T_);

    // swizzled frag-read offsets (elements)
    const int x0 = 8 * ((h)     ^ (l15 & 7));
    const int x1 = 8 * ((4 + h) ^ (l15 & 7));
    const int rb = l15 * 64;

    // staging: row r0 = tid>>3, 16B block xor'd with row
    const int r0 = tid >> 3;
    const int kx = (tid & 7) ^ (r0 & 7);
    const unsigned short* ksrc0 = Ktb + (size_t)r0 * 64 + 8 * kx;
    const unsigned short* vsrc0 = Vbb + (size_t)r0 * T_ + 8 * kx;

    // hoisted Q B-frags, scaled by 0.125*log2(e) (exp2-direct softmax)
    short8 aq[2][2];
#pragma unroll
    for (int ts = 0; ts < 2; ++ts)
#pragma unroll
        for (int ch = 0; ch < 2; ++ch) {
            short8 q;
#pragma unroll
            for (int j = 0; j < 8; ++j)
                q[j] = (short)f2bf(0.180336880f *
                        Qp[(size_t)(32 * ch + 8 * h + j) * T_ + tb + 16 * ts + l15]);
            aq[ts][ch] = q;
        }

    f32x4 o[4][2];
#pragma unroll
    for (int cs = 0; cs < 4; ++cs)
#pragma unroll
        for (int ts = 0; ts < 2; ++ts) o[cs][ts] = (f32x4){0.f, 0.f, 0.f, 0.f};
    float dsum[2] = {0.f, 0.f};
    const f32x4 zero4 = {0.f, 0.f, 0.f, 0.f};

    // prologue: stage tile 0 into buf 0
    gl_lds16(ksrc0,                   &Ks[0][wid * 512]);
    gl_lds16(ksrc0 + 32 * 64,         &Ks[0][wid * 512 + 2048]);
    gl_lds16(vsrc0,                   &Vs[0][wid * 512]);
    gl_lds16(vsrc0 + (size_t)32 * T_, &Vs[0][wid * 512 + 2048]);

    for (int it = 0; it < NIT; ++it) {
        __syncthreads();                       // tile staged, prev reads done
        const int buf = it & 1;
        if (it + 1 < NIT) {
            const int s1 = (it + 1) * SB;
            const int bo = (buf ^ 1) * 4096;
            gl_lds16(ksrc0 + (size_t)s1 * 64,        &Ks[0][bo + wid * 512]);
            gl_lds16(ksrc0 + (size_t)(s1 + 32) * 64, &Ks[0][bo + wid * 512 + 2048]);
            gl_lds16(vsrc0 + s1,                     &Vs[0][bo + wid * 512]);
            gl_lds16(vsrc0 + (size_t)32 * T_ + s1,   &Vs[0][bo + wid * 512 + 2048]);
        }
        const unsigned short* kb = &Ks[buf][0];
        const unsigned short* vb = &Vs[buf][0];

        __builtin_amdgcn_s_setprio(1);

        // ---- QK^T (swapped), ALL 16 MFMAs: W[s][t], s=16ss+4h+r, t=tb+16ts+l15 ----
        f32x4 w[2][4];
#pragma unroll
        for (int ss = 0; ss < 4; ++ss) {
            const short8 bk0 = ld_contig(kb + rb + ss * 1024 + x0);
            const short8 bk1 = ld_contig(kb + rb + ss * 1024 + x1);
#pragma unroll
            for (int ts = 0; ts < 2; ++ts) {
                f32x4 acc = zero4;
                acc = __builtin_amdgcn_mfma_f32_16x16x32_bf16(bk0, aq[ts][0], acc, 0, 0, 0);
                acc = __builtin_amdgcn_mfma_f32_16x16x32_bf16(bk1, aq[ts][1], acc, 0, 0, 0);
                w[ts][ss] = acc;
            }
        }

        // ---- softmax + in-register transpose, both halves (overlaps MFMA tail) ----
        short8 pb[2][2];
#pragma unroll
        for (int half = 0; half < 2; ++half)
#pragma unroll
            for (int ts = 0; ts < 2; ++ts) {
                float e0[4], e1[4];
#pragma unroll
                for (int r = 0; r < 4; ++r) {
                    e0[r] = vexp2(w[ts][2 * half + 0][r]);
                    e1[r] = vexp2(w[ts][2 * half + 1][r]);
                }
                dsum[ts] += ((e0[0] + e0[1]) + (e0[2] + e0[3]))
                          + ((e1[0] + e1[1]) + (e1[2] + e1[3]));
                unsigned a0 = cvtpk(e0[0], e0[1]);
                unsigned a1 = cvtpk(e0[2], e0[3]);
                unsigned b0 = cvtpk(e1[0], e1[1]);
                unsigned b1 = cvtpk(e1[2], e1[3]);
                pl_swap(a0, b0);
                pl_swap(a1, b1);
                union { short8 s8; unsigned u[4]; } u;
                u.u[0] = a0; u.u[1] = a1; u.u[2] = b0; u.u[3] = b1;
                pb[ts][half] = u.s8;
            }

        // ---- PV: O[c][t] += V[c][s] * P^T[s][t] ----
#pragma unroll
        for (int cs = 0; cs < 4; ++cs) {
            const short8 av0 = ld_contig(vb + rb + cs * 1024 + x0);
            const short8 av1 = ld_contig(vb + rb + cs * 1024 + x1);
#pragma unroll
            for (int ts = 0; ts < 2; ++ts) {
                o[cs][ts] = __builtin_amdgcn_mfma_f32_16x16x32_bf16(av0, pb[ts][0], o[cs][ts], 0, 0, 0);
                o[cs][ts] = __builtin_amdgcn_mfma_f32_16x16x32_bf16(av1, pb[ts][1], o[cs][ts], 0, 0, 0);
            }
        }
        __builtin_amdgcn_s_setprio(0);
    }

    // ---- denominator: reduce partial sums across the 4 h-groups ----
    float inv[2];
#pragma unroll
    for (int ts = 0; ts < 2; ++ts) {
        float d = dsum[ts];
        d += __shfl_xor(d, 16, 64);
        d += __shfl_xor(d, 32, 64);
        inv[ts] = 1.0f / d;
    }

    // ---- epilogue: O-frag row=c=16cs+4h+r, col=t=tb+16ts+l15 ----
    float* outp = out + (size_t)b * CH_ * T_;
#pragma unroll
    for (int cs = 0; cs < 4; ++cs)
#pragma unroll
        for (int r = 0; r < 4; ++r) {
            const size_t row = (size_t)(16 * cs + 4 * h + r) * T_;
            outp[row + tb + l15]      = o[cs][0][r] * inv[0];
            outp[row + tb + 16 + l15] = o[cs][1][r] * inv[1];
        }
}

// ---------------- fallback (round-1 kernel, used if ws too small) ----------------
__global__ __launch_bounds__(256) void qkv_attn_fb(const float* __restrict__ qkv,
                                                   float* __restrict__ out)
{
    __shared__ unsigned short Qs[CH_][68];
    __shared__ unsigned short Ksf[CH_][68];
    __shared__ unsigned short Vsf[CH_][72];
    __shared__ unsigned short Psf[4][64][18];

    const int tid  = threadIdx.x;
    const int lane = tid & 63;
    const int wid  = tid >> 6;
    const int l15  = lane & 15;
    const int h    = lane >> 4;
    const int bidx = blockIdx.x;
    const int b    = bidx >> 5;
    const int t0   = (bidx & 31) * 64;
    const int tw   = wid * 16;

    const float* Qp = qkv + (size_t)b * (3 * CH_ * T_);
    const float* Kp = Qp + CH_ * T_;
    const float* Vp = Kp + CH_ * T_;

    const int srow = tid >> 4;
    const int scol = (tid & 15) << 2;

#pragma unroll
    for (int i = 0; i < 4; ++i) {
        const int c = srow + 16 * i;
        const float4 q = *(const float4*)(Qp + (size_t)c * T_ + t0 + scol);
        us4 w; w[0] = f2bf(q.x); w[1] = f2bf(q.y); w[2] = f2bf(q.z); w[3] = f2bf(q.w);
        *(us4*)(&Qs[c][scol]) = w;
    }
    __syncthreads();

    const short8 aq0 = ld_strided(&Qs[0 + 8 * h][tw + l15], 68);
    const short8 aq1 = ld_strided(&Qs[32 + 8 * h][tw + l15], 68);

    short8 aones;
#pragma unroll
    for (int j = 0; j < 8; ++j) aones[j] = (short)0x3F80;

    f32x4 o[4];
#pragma unroll
    for (int cs = 0; cs < 4; ++cs) o[cs] = (f32x4){0.f, 0.f, 0.f, 0.f};
    float l_run = 0.0f;
    const f32x4 zero4 = {0.f, 0.f, 0.f, 0.f};

    for (int it = 0; it < 32; ++it) {
        const int s0 = it * 64;
        __syncthreads();
#pragma unroll
        for (int i = 0; i < 4; ++i) {
            const int c = srow + 16 * i;
            const float4 kv = *(const float4*)(Kp + (size_t)c * T_ + s0 + scol);
            us4 wk; wk[0] = f2bf(kv.x); wk[1] = f2bf(kv.y); wk[2] = f2bf(kv.z); wk[3] = f2bf(kv.w);
            *(us4*)(&Ksf[c][scol]) = wk;
            const float4 vv = *(const float4*)(Vp + (size_t)c * T_ + s0 + scol);
            us4 wv; wv[0] = f2bf(vv.x); wv[1] = f2bf(vv.y); wv[2] = f2bf(vv.z); wv[3] = f2bf(vv.w);
            *(us4*)(&Vsf[c][scol]) = wv;
        }
        __syncthreads();

        f32x4 w[4];
#pragma unroll
        for (int ss = 0; ss < 4; ++ss) {
            const short8 bkl = ld_strided(&Ksf[0 + 8 * h][ss * 16 + l15], 68);
            const short8 bkh = ld_strided(&Ksf[32 + 8 * h][ss * 16 + l15], 68);
            f32x4 acc = zero4;
            acc = __builtin_amdgcn_mfma_f32_16x16x32_bf16(aq0, bkl, acc, 0, 0, 0);
            acc = __builtin_amdgcn_mfma_f32_16x16x32_bf16(aq1, bkh, acc, 0, 0, 0);
            w[ss] = acc;
        }

#pragma unroll
        for (int ss = 0; ss < 4; ++ss) {
            const float e0 = __expf(0.125f * w[ss][0]);
            const float e1 = __expf(0.125f * w[ss][1]);
            const float e2 = __expf(0.125f * w[ss][2]);
            const float e3 = __expf(0.125f * w[ss][3]);
            const unsigned p01 = (unsigned)f2bf(e0) | ((unsigned)f2bf(e1) << 16);
            const unsigned p23 = (unsigned)f2bf(e2) | ((unsigned)f2bf(e3) << 16);
            const int s = ss * 16 + l15;
            *(unsigned*)(&Psf[wid][s][4 * h]) = p01;
            *(unsigned*)(&Psf[wid][s][4 * h + 2]) = p23;
        }

        const short8 pb0 = ld_strided(&Psf[wid][0 + 8 * h][l15], 18);
        const short8 pb1 = ld_strided(&Psf[wid][32 + 8 * h][l15], 18);

        f32x4 lacc = zero4;
        lacc = __builtin_amdgcn_mfma_f32_16x16x32_bf16(aones, pb0, lacc, 0, 0, 0);
        lacc = __builtin_amdgcn_mfma_f32_16x16x32_bf16(aones, pb1, lacc, 0, 0, 0);
        l_run += lacc[0];

#pragma unroll
        for (int cs = 0; cs < 4; ++cs) {
            const short8 av0 = ld_contig(&Vsf[cs * 16 + l15][0 + 8 * h]);
            const short8 av1 = ld_contig(&Vsf[cs * 16 + l15][32 + 8 * h]);
            o[cs] = __builtin_amdgcn_mfma_f32_16x16x32_bf16(av0, pb0, o[cs], 0, 0, 0);
            o[cs] = __builtin_amdgcn_mfma_f32_16x16x32_bf16(av1, pb1, o[cs], 0, 0, 0);
        }
    }

    const float invd = 1.0f / l_run;
    float* outp = out + (size_t)b * CH_ * T_;
#pragma unroll
    for (int cs = 0; cs < 4; ++cs)
#pragma unroll
        for (int r = 0; r < 4; ++r)
            outp[(size_t)(cs * 16 + 4 * h + r) * T_ + t0 + tw + l15] = o[cs][r] * invd;
}

extern "C" void kernel_launch(void* const* d_in, const int* in_sizes, int n_in,
                              void* d_out, int out_size, void* d_ws, size_t ws_size,
                              hipStream_t stream) {
    const float* qkv = (const float*)d_in[0];
    float* outp = (float*)d_out;
    const size_t need = (size_t)2 * B_ * CH_ * T_ * sizeof(unsigned short); // 32 MB
    if (ws_size >= need) {
        unsigned short* Ktg = (unsigned short*)d_ws;
        unsigned short* Vbg = Ktg + (size_t)B_ * T_ * CH_;
        qkv_prep<<<dim3(B_ * 32), dim3(256), 0, stream>>>(qkv, Ktg, Vbg);
        qkv_attn7<<<dim3(B_ * (T_ / TQ)), dim3(256), 0, stream>>>(qkv, Ktg, Vbg, outp);
    } else {
        qkv_attn_fb<<<dim3(B_ * 32), dim3(256), 0, stream>>>(qkv, outp);
    }
}